// Round 1
// baseline (818.569 us; speedup 1.0000x reference)
//
#include <hip/hip_runtime.h>
#include <cstdint>

#define NNODES 40000
#define INDIM 2000
#define HIDD 512
#define ODIM 30
#define NEDGES 400000
#define KPAD 2048

typedef short bf16x8 __attribute__((ext_vector_type(8)));
typedef float f32x4 __attribute__((ext_vector_type(4)));

__device__ __forceinline__ float bf2f(ushort u){ union{unsigned int i; float f;} x; x.i = ((unsigned int)u)<<16; return x.f; }
__device__ __forceinline__ ushort f2bf(float v){ union{float f; unsigned int u;} x; x.f=v; unsigned int r = x.u + 0x7fffu + ((x.u>>16)&1u); return (ushort)(r>>16); }

// ---------------- casts ----------------
__global__ __launch_bounds__(256) void cast_feat_kernel(const float* __restrict__ src, ushort* __restrict__ dstb){
  int c = blockIdx.x*256 + threadIdx.x;          // chunk of 8 elems; 40000*256 chunks
  int row = c >> 8, kc = c & 255;
  bf16x8 o;
  if (kc < INDIM/8) {
    const float* p = src + (size_t)row*INDIM + kc*8;
    #pragma unroll
    for (int j=0;j<8;++j) o[j] = (short)f2bf(p[j]);
  } else {
    #pragma unroll
    for (int j=0;j<8;++j) o[j] = 0;
  }
  *(bf16x8*)(dstb + (size_t)row*KPAD + kc*8) = o;
}

__global__ __launch_bounds__(256) void cast_w1_kernel(const float* __restrict__ W1, ushort* __restrict__ W1b, ushort* __restrict__ W1t){
  int idx = blockIdx.x*256 + threadIdx.x;        // 2000*512
  if (idx >= INDIM*HIDD) return;
  int r = idx >> 9, c = idx & 511;
  ushort b = f2bf(W1[idx]);
  W1b[idx] = b;
  W1t[(size_t)c*KPAD + r] = b;                   // pad cols [2000,2048) pre-zeroed
}

__global__ __launch_bounds__(256) void cast_w2_kernel(const float* __restrict__ W2, ushort* __restrict__ W2p){
  int idx = blockIdx.x*256 + threadIdx.x;        // 512*30
  if (idx >= HIDD*ODIM) return;
  int k = idx / ODIM, c = idx - k*ODIM;
  W2p[k*32 + c] = f2bf(W2[idx]);                 // cols 30,31 pre-zeroed
}

// ---------------- CSR build ----------------
__global__ __launch_bounds__(256) void hist_kernel(const int* __restrict__ dst, int* __restrict__ deg){
  int e = blockIdx.x*256 + threadIdx.x;
  if (e < NEDGES) atomicAdd(&deg[dst[e]], 1);
}

__global__ __launch_bounds__(1024) void scan_kernel(const int* __restrict__ deg, int* __restrict__ row_ptr){
  __shared__ int buf[1024];
  __shared__ int s_carry;
  const int t = threadIdx.x;
  if (t == 0) s_carry = 0;
  __syncthreads();
  for (int base = 0; base <= NNODES; base += 1024) {
    int idx = base + t;
    int v = (idx < NNODES) ? deg[idx] : 0;
    buf[t] = v; __syncthreads();
    #pragma unroll
    for (int off = 1; off < 1024; off <<= 1) {
      int x = (t >= off) ? buf[t-off] : 0;
      __syncthreads();
      buf[t] += x;
      __syncthreads();
    }
    int incl = buf[t];
    int excl = incl - v + s_carry;
    if (idx <= NNODES) row_ptr[idx] = excl;
    __syncthreads();
    if (t == 1023) s_carry += incl;
    __syncthreads();
  }
}

__global__ __launch_bounds__(256) void place_kernel(const int* __restrict__ src, const int* __restrict__ dst,
    const int* __restrict__ row_ptr, int* __restrict__ cursor, int* __restrict__ csr_src){
  int e = blockIdx.x*256 + threadIdx.x;
  if (e >= NEDGES) return;
  int d = dst[e];
  int pos = row_ptr[d] + atomicAdd(&cursor[d], 1);
  csr_src[pos] = src[e];
}

// ---------------- bf16 MFMA GEMM, Bt form: C[M][N] = A[M][K] * Bt[N][K]^T ----------------
template<typename OutT>
__global__ __launch_bounds__(256, 2) void gemm_bt_kernel(
    const ushort* __restrict__ A, const ushort* __restrict__ Bt,
    OutT* __restrict__ C, int M, int N, int K, int ldc)
{
  __shared__ ushort As[128*64];
  __shared__ ushort Bs[128*64];
  const int tid = threadIdx.x;
  const int lane = tid & 63;
  const int w = tid >> 6;
  const int wm = w >> 1, wn = w & 1;
  const int row0 = blockIdx.x * 128;
  const int col0 = blockIdx.y * 128;
  f32x4 acc[4][4] = {};

  for (int k0 = 0; k0 < K; k0 += 64) {
    #pragma unroll
    for (int it = 0; it < 4; ++it) {
      int ch = tid + it*256;                 // 0..1023 chunks of 16B
      int r = ch >> 3, k8 = (ch & 7) * 8;
      int ra = row0 + r; ra = ra < M ? ra : M-1;
      int rb = col0 + r; rb = rb < N ? rb : N-1;
      __builtin_amdgcn_global_load_lds(
        (const __attribute__((address_space(1))) unsigned int*)(A + (size_t)ra*K + k0 + k8),
        (__attribute__((address_space(3))) unsigned int*)(&As[ch*8]), 16, 0, 0);
      __builtin_amdgcn_global_load_lds(
        (const __attribute__((address_space(1))) unsigned int*)(Bt + (size_t)rb*K + k0 + k8),
        (__attribute__((address_space(3))) unsigned int*)(&Bs[ch*8]), 16, 0, 0);
    }
    __syncthreads();
    #pragma unroll
    for (int kk = 0; kk < 2; ++kk) {
      bf16x8 af[4], bfr[4];
      const int ko = kk*32 + (lane>>4)*8;
      #pragma unroll
      for (int i=0;i<4;++i) af[i] = *(const bf16x8*)&As[(wm*64 + i*16 + (lane&15))*64 + ko];
      #pragma unroll
      for (int j=0;j<4;++j) bfr[j] = *(const bf16x8*)&Bs[(wn*64 + j*16 + (lane&15))*64 + ko];
      #pragma unroll
      for (int i=0;i<4;++i)
        #pragma unroll
        for (int j=0;j<4;++j)
          acc[i][j] = __builtin_amdgcn_mfma_f32_16x16x32_bf16(af[i], bfr[j], acc[i][j], 0, 0, 0);
    }
    __syncthreads();
  }
  const int rbase = row0 + wm*64 + (lane>>4)*4;
  const int cbase = col0 + wn*64 + (lane&15);
  #pragma unroll
  for (int i=0;i<4;++i){
    #pragma unroll
    for (int j=0;j<4;++j){
      #pragma unroll
      for (int reg=0;reg<4;++reg){
        int r = rbase + i*16 + reg;
        int cc = cbase + j*16;
        if (r < M && cc < N){
          if constexpr (sizeof(OutT)==4) C[(size_t)r*ldc + cc] = acc[i][j][reg];
          else                           C[(size_t)r*ldc + cc] = f2bf(acc[i][j][reg]);
        }
      }
    }
  }
}

// ---------------- a_src/a_dst: per-row dot with att vectors ----------------
__global__ __launch_bounds__(256) void a_kernel(const ushort* __restrict__ x1,
    const float* __restrict__ att_src, const float* __restrict__ att_dst,
    float* __restrict__ a_src, float* __restrict__ a_dst){
  int gid = blockIdx.x*256 + threadIdx.x;
  int row = gid >> 6, lane = gid & 63;
  if (row >= NNODES) return;
  bf16x8 v = *(const bf16x8*)(x1 + (size_t)row*HIDD + lane*8);
  float ps = 0.f, pd = 0.f;
  #pragma unroll
  for (int j=0;j<8;++j){
    float xv = bf2f((ushort)v[j]);
    ps += xv * att_src[lane*8+j];
    pd += xv * att_dst[lane*8+j];
  }
  #pragma unroll
  for (int off=32; off>0; off>>=1){ ps += __shfl_down(ps, off); pd += __shfl_down(pd, off); }
  if (lane == 0){ a_src[row] = ps; a_dst[row] = pd; }
}

// ---------------- per-node segment softmax over CSR edges ----------------
__global__ __launch_bounds__(256) void alpha_kernel(const int* __restrict__ row_ptr,
    const int* __restrict__ csr_src, const float* __restrict__ a_src,
    const float* __restrict__ a_dst, float* __restrict__ csr_alpha){
  int gid = blockIdx.x*256 + threadIdx.x;
  int v = gid >> 6, lane = gid & 63;
  if (v >= NNODES) return;
  int p0 = row_ptr[v], p1 = row_ptr[v+1];
  if (p0 >= p1) return;
  float ad = a_dst[v];
  float m = -1e30f;
  for (int p = p0 + lane; p < p1; p += 64){
    float s = 1.f/(1.f + __expf(-(a_src[csr_src[p]] + ad)));
    m = fmaxf(m, s);
  }
  #pragma unroll
  for (int off=32; off>0; off>>=1) m = fmaxf(m, __shfl_xor(m, off));
  float sum = 0.f;
  for (int p = p0 + lane; p < p1; p += 64){
    float s = 1.f/(1.f + __expf(-(a_src[csr_src[p]] + ad)));
    float e = __expf(s - m);
    csr_alpha[p] = e;
    sum += e;
  }
  #pragma unroll
  for (int off=32; off>0; off>>=1) sum += __shfl_xor(sum, off);
  float inv = 1.f/(sum + 1e-16f);
  for (int p = p0 + lane; p < p1; p += 64) csr_alpha[p] *= inv;
}

// ---------------- aggregate: out[v] = elu( sum_e alpha_e * X[src_e] ) ----------------
__global__ __launch_bounds__(128) void agg_kernel(const ushort* __restrict__ X,
    const int* __restrict__ row_ptr, const int* __restrict__ csr_src,
    const float* __restrict__ csr_alpha, ushort* __restrict__ outb){
  int v = blockIdx.x;
  int t = threadIdx.x;
  int p0 = row_ptr[v], p1 = row_ptr[v+1];
  float a0=0.f,a1=0.f,a2=0.f,a3=0.f;
  for (int p=p0; p<p1; ++p){
    int s = csr_src[p];
    float al = csr_alpha[p];
    const ushort4 xv = *(const ushort4*)(X + (size_t)s*HIDD + t*4);
    a0 += al*bf2f(xv.x); a1 += al*bf2f(xv.y); a2 += al*bf2f(xv.z); a3 += al*bf2f(xv.w);
  }
  a0 = a0 > 0.f ? a0 : __expf(a0)-1.f;
  a1 = a1 > 0.f ? a1 : __expf(a1)-1.f;
  a2 = a2 > 0.f ? a2 : __expf(a2)-1.f;
  a3 = a3 > 0.f ? a3 : __expf(a3)-1.f;
  ushort4 o; o.x=f2bf(a0); o.y=f2bf(a1); o.z=f2bf(a2); o.w=f2bf(a3);
  *(ushort4*)(outb + (size_t)v*HIDD + t*4) = o;
}

// ---------------- h2 = h1 @ W2 (K=512, N=30) ----------------
__global__ __launch_bounds__(256) void mid_kernel(const ushort* __restrict__ h1,
    const float* __restrict__ W2, float* __restrict__ h2){
  __shared__ ushort h1s[32*512];
  __shared__ ushort w2t[30*520];
  const int t = threadIdx.x;
  const int row0 = blockIdx.x * 32;
  const ushort* g = h1 + (size_t)row0*HIDD;
  #pragma unroll
  for (int it=0; it<8; ++it){
    int ch = t + it*256;
    *(bf16x8*)&h1s[ch*8] = *(const bf16x8*)&g[ch*8];
  }
  for (int idx = t; idx < HIDD*ODIM; idx += 256){
    int k = idx / ODIM, c = idx - k*ODIM;
    w2t[c*520 + k] = f2bf(W2[idx]);
  }
  __syncthreads();
  int c = t & 31, rg = t >> 5;
  if (c < ODIM){
    float acc[4] = {0.f,0.f,0.f,0.f};
    for (int k0=0;k0<64;++k0){
      bf16x8 wv = *(const bf16x8*)&w2t[c*520 + k0*8];
      #pragma unroll
      for (int rr=0; rr<4; ++rr){
        bf16x8 hv = *(const bf16x8*)&h1s[(rg*4+rr)*HIDD + k0*8];
        #pragma unroll
        for (int j=0;j<8;++j) acc[rr] += bf2f((ushort)hv[j]) * bf2f((ushort)wv[j]);
      }
    }
    #pragma unroll
    for (int rr=0;rr<4;++rr) h2[(size_t)(row0 + rg*4 + rr)*ODIM + c] = acc[rr];
  }
}

// ---------------- x3 = h2 @ W2^T (K=30, N=512) ----------------
__global__ __launch_bounds__(256) void x3_kernel(const float* __restrict__ h2,
    const ushort* __restrict__ W2p, ushort* __restrict__ x3){
  int gid = blockIdx.x*256 + threadIdx.x;
  int row = gid >> 6, lane = gid & 63;
  if (row >= NNODES) return;
  float h[ODIM];
  #pragma unroll
  for (int ci=0; ci<ODIM; ++ci) h[ci] = h2[(size_t)row*ODIM + ci];
  #pragma unroll
  for (int it=0; it<8; ++it){
    int n = it*64 + lane;
    const ushort* wr = W2p + n*32;
    bf16x8 wvv[4];
    #pragma unroll
    for (int q=0;q<4;++q) wvv[q] = *(const bf16x8*)(wr + q*8);
    float acc = 0.f;
    #pragma unroll
    for (int ci=0; ci<ODIM; ++ci) acc += h[ci]*bf2f((ushort)wvv[ci>>3][ci&7]);
    x3[(size_t)row*HIDD + n] = f2bf(acc);
  }
}

extern "C" void kernel_launch(void* const* d_in, const int* in_sizes, int n_in,
                              void* d_out, int out_size, void* d_ws, size_t ws_size,
                              hipStream_t stream){
  const float* features = (const float*)d_in[0];
  const float* W1 = (const float*)d_in[1];
  const float* W2 = (const float*)d_in[2];
  const float* att_src = (const float*)d_in[3];
  const float* att_dst = (const float*)d_in[4];
  const int* edge = (const int*)d_in[5];
  const int* esrc = edge;
  const int* edst = edge + NEDGES;

  float* h2 = (float*)d_out;                              // [40000][30]
  float* h4 = h2 + (size_t)NNODES*ODIM;                   // [40000][2000]
  char* obase = (char*)h4;                                // 320 MB region, scratch until GEMM4
  ushort* featb = (ushort*)obase;                         // [40000][2048] bf16 = 163.84 MB
  ushort* x1b   = (ushort*)(obase + 163840000);           // [40000][512]  bf16 = 40.96 MB
  ushort* h1b   = (ushort*)(obase + 204800000);
  ushort* x3b   = (ushort*)(obase + 245760000);           // ends at 286.72 MB < 320 MB

  char* wbase = (char*)d_ws;
  size_t o = 0;
  auto walloc = [&](size_t bytes)->void*{ void* p = wbase + o; o += (bytes + 255) & ~(size_t)255; return p; };
  ushort* h3b      = (ushort*)walloc((size_t)NNODES*HIDD*2);
  ushort* W1b      = (ushort*)walloc((size_t)INDIM*HIDD*2);
  ushort* W1t      = (ushort*)walloc((size_t)HIDD*KPAD*2);
  ushort* W2p      = (ushort*)walloc(512*32*2);
  float*  a_src    = (float*)walloc(NNODES*4);
  float*  a_dst    = (float*)walloc(NNODES*4);
  int*    deg      = (int*)walloc(NNODES*4);
  int*    cursor   = (int*)walloc(NNODES*4);
  int*    row_ptr  = (int*)walloc((NNODES+1)*4);
  int*    csr_src  = (int*)walloc(NEDGES*4);
  float*  csr_alpha= (float*)walloc(NEDGES*4);

  hipMemsetAsync(deg, 0, NNODES*4, stream);
  hipMemsetAsync(cursor, 0, NNODES*4, stream);
  hipMemsetAsync(W1t, 0, (size_t)HIDD*KPAD*2, stream);
  hipMemsetAsync(W2p, 0, 512*32*2, stream);

  cast_feat_kernel<<<40000, 256, 0, stream>>>(features, featb);
  cast_w1_kernel<<<(INDIM*HIDD+255)/256, 256, 0, stream>>>(W1, W1b, W1t);
  cast_w2_kernel<<<(HIDD*ODIM+255)/256, 256, 0, stream>>>(W2, W2p);
  hist_kernel<<<(NEDGES+255)/256, 256, 0, stream>>>(edst, deg);
  scan_kernel<<<1, 1024, 0, stream>>>(deg, row_ptr);
  place_kernel<<<(NEDGES+255)/256, 256, 0, stream>>>(esrc, edst, row_ptr, cursor, csr_src);

  gemm_bt_kernel<ushort><<<dim3(313, 4), 256, 0, stream>>>(featb, W1t, x1b, NNODES, HIDD, KPAD, HIDD);
  a_kernel<<<10000, 256, 0, stream>>>(x1b, att_src, att_dst, a_src, a_dst);
  alpha_kernel<<<10000, 256, 0, stream>>>(row_ptr, csr_src, a_src, a_dst, csr_alpha);
  agg_kernel<<<NNODES, 128, 0, stream>>>(x1b, row_ptr, csr_src, csr_alpha, h1b);
  mid_kernel<<<NNODES/32, 256, 0, stream>>>(h1b, W2, h2);
  x3_kernel<<<10000, 256, 0, stream>>>(h2, W2p, x3b);
  agg_kernel<<<NNODES, 128, 0, stream>>>(x3b, row_ptr, csr_src, csr_alpha, h3b);
  gemm_bt_kernel<float><<<dim3(313, 16), 256, 0, stream>>>(h3b, W1b, h4, NNODES, INDIM, HIDD, INDIM);
}

// Round 2
// 775.574 us; speedup vs baseline: 1.0554x; 1.0554x over previous
//
#include <hip/hip_runtime.h>
#include <cstdint>

#define NNODES 40000
#define INDIM 2000
#define HIDD 512
#define ODIM 30
#define NEDGES 400000
#define KPAD 2048

typedef short bf16x8 __attribute__((ext_vector_type(8)));
typedef float f32x4 __attribute__((ext_vector_type(4)));

__device__ __forceinline__ float bf2f(ushort u){ union{unsigned int i; float f;} x; x.i = ((unsigned int)u)<<16; return x.f; }
__device__ __forceinline__ ushort f2bf(float v){ union{float f; unsigned int u;} x; x.f=v; unsigned int r = x.u + 0x7fffu + ((x.u>>16)&1u); return (ushort)(r>>16); }

// ---------------- casts ----------------
__global__ __launch_bounds__(256) void cast_feat_kernel(const float* __restrict__ src, ushort* __restrict__ dstb){
  int c = blockIdx.x*256 + threadIdx.x;          // chunk of 8 elems; 40000*256 chunks
  int row = c >> 8, kc = c & 255;
  bf16x8 o;
  if (kc < INDIM/8) {
    const float* p = src + (size_t)row*INDIM + kc*8;
    #pragma unroll
    for (int j=0;j<8;++j) o[j] = (short)f2bf(p[j]);
  } else {
    #pragma unroll
    for (int j=0;j<8;++j) o[j] = 0;
  }
  *(bf16x8*)(dstb + (size_t)row*KPAD + kc*8) = o;
}

__global__ __launch_bounds__(256) void cast_w1_kernel(const float* __restrict__ W1, ushort* __restrict__ W1b, ushort* __restrict__ W1t){
  int idx = blockIdx.x*256 + threadIdx.x;        // 2000*512
  if (idx >= INDIM*HIDD) return;
  int r = idx >> 9, c = idx & 511;
  ushort b = f2bf(W1[idx]);
  W1b[idx] = b;
  W1t[(size_t)c*KPAD + r] = b;                   // pad cols [2000,2048) pre-zeroed
}

__global__ __launch_bounds__(256) void cast_w2_kernel(const float* __restrict__ W2, ushort* __restrict__ W2p, ushort* __restrict__ W2tc){
  int idx = blockIdx.x*256 + threadIdx.x;        // 512*32 padded
  if (idx >= HIDD*32) return;
  int k = idx >> 5, c = idx & 31;
  float val = (c < ODIM) ? W2[k*ODIM + c] : 0.f;
  ushort b = f2bf(val);
  W2p[k*32 + c] = b;                             // [512][32] k-major
  W2tc[c*HIDD + k] = b;                          // [32][512] c-major (rows 30,31 zero)
}

// ---------------- CSR build ----------------
__global__ __launch_bounds__(256) void hist_kernel(const int* __restrict__ dst, int* __restrict__ deg){
  int e = blockIdx.x*256 + threadIdx.x;
  if (e < NEDGES) atomicAdd(&deg[dst[e]], 1);
}

// one block, 1024 threads; each thread sequentially scans 40 elements in regs,
// one 10-round block scan over the 1024 partials (~25 barriers total).
__global__ __launch_bounds__(1024) void scan_kernel(const int* __restrict__ deg, int* __restrict__ row_ptr){
  __shared__ int part[1024];
  const int t = threadIdx.x;
  const int base = t * 40;
  int v[40];
  int s = 0;
  #pragma unroll
  for (int j=0;j<40;++j){
    int i = base + j;
    int d = (i < NNODES) ? deg[i] : 0;
    v[j] = s;                 // exclusive within-thread prefix
    s += d;
  }
  part[t] = s;
  __syncthreads();
  #pragma unroll
  for (int off=1; off<1024; off<<=1){
    int x = (t >= off) ? part[t-off] : 0;
    __syncthreads();
    part[t] += x;
    __syncthreads();
  }
  int offset = (t > 0) ? part[t-1] : 0;
  #pragma unroll
  for (int j=0;j<40;++j){
    int i = base + j;
    if (i <= NNODES) row_ptr[i] = offset + v[j];
  }
}

__global__ __launch_bounds__(256) void place_kernel(const int* __restrict__ src, const int* __restrict__ dst,
    const int* __restrict__ row_ptr, int* __restrict__ cursor, int* __restrict__ csr_src){
  int e = blockIdx.x*256 + threadIdx.x;
  if (e >= NEDGES) return;
  int d = dst[e];
  int pos = row_ptr[d] + atomicAdd(&cursor[d], 1);
  csr_src[pos] = src[e];
}

// ---------------- bf16 MFMA GEMM, Bt form: C[M][N] = A[M][K] * Bt[N][K]^T ----------------
template<typename OutT>
__global__ __launch_bounds__(256, 2) void gemm_bt_kernel(
    const ushort* __restrict__ A, const ushort* __restrict__ Bt,
    OutT* __restrict__ C, int M, int N, int K, int ldc)
{
  __shared__ ushort As[128*64];
  __shared__ ushort Bs[128*64];
  const int tid = threadIdx.x;
  const int lane = tid & 63;
  const int w = tid >> 6;
  const int wm = w >> 1, wn = w & 1;
  const int row0 = blockIdx.x * 128;
  const int col0 = blockIdx.y * 128;
  f32x4 acc[4][4] = {};

  for (int k0 = 0; k0 < K; k0 += 64) {
    #pragma unroll
    for (int it = 0; it < 4; ++it) {
      int ch = tid + it*256;                 // 0..1023 chunks of 16B
      int r = ch >> 3, k8 = (ch & 7) * 8;
      int ra = row0 + r; ra = ra < M ? ra : M-1;
      int rb = col0 + r; rb = rb < N ? rb : N-1;
      __builtin_amdgcn_global_load_lds(
        (const __attribute__((address_space(1))) unsigned int*)(A + (size_t)ra*K + k0 + k8),
        (__attribute__((address_space(3))) unsigned int*)(&As[ch*8]), 16, 0, 0);
      __builtin_amdgcn_global_load_lds(
        (const __attribute__((address_space(1))) unsigned int*)(Bt + (size_t)rb*K + k0 + k8),
        (__attribute__((address_space(3))) unsigned int*)(&Bs[ch*8]), 16, 0, 0);
    }
    __syncthreads();
    #pragma unroll
    for (int kk = 0; kk < 2; ++kk) {
      bf16x8 af[4], bfr[4];
      const int ko = kk*32 + (lane>>4)*8;
      #pragma unroll
      for (int i=0;i<4;++i) af[i] = *(const bf16x8*)&As[(wm*64 + i*16 + (lane&15))*64 + ko];
      #pragma unroll
      for (int j=0;j<4;++j) bfr[j] = *(const bf16x8*)&Bs[(wn*64 + j*16 + (lane&15))*64 + ko];
      #pragma unroll
      for (int i=0;i<4;++i)
        #pragma unroll
        for (int j=0;j<4;++j)
          acc[i][j] = __builtin_amdgcn_mfma_f32_16x16x32_bf16(af[i], bfr[j], acc[i][j], 0, 0, 0);
    }
    __syncthreads();
  }
  const int rbase = row0 + wm*64 + (lane>>4)*4;
  const int cbase = col0 + wn*64 + (lane&15);
  #pragma unroll
  for (int i=0;i<4;++i){
    #pragma unroll
    for (int j=0;j<4;++j){
      #pragma unroll
      for (int reg=0;reg<4;++reg){
        int r = rbase + i*16 + reg;
        int cc = cbase + j*16;
        if (r < M && cc < N){
          if constexpr (sizeof(OutT)==4) C[(size_t)r*ldc + cc] = acc[i][j][reg];
          else                           C[(size_t)r*ldc + cc] = f2bf(acc[i][j][reg]);
        }
      }
    }
  }
}

// ---------------- a_src/a_dst: per-row dot with att vectors ----------------
__global__ __launch_bounds__(256) void a_kernel(const ushort* __restrict__ x1,
    const float* __restrict__ att_src, const float* __restrict__ att_dst,
    float* __restrict__ a_src, float* __restrict__ a_dst){
  int gid = blockIdx.x*256 + threadIdx.x;
  int row = gid >> 6, lane = gid & 63;
  if (row >= NNODES) return;
  bf16x8 v = *(const bf16x8*)(x1 + (size_t)row*HIDD + lane*8);
  float ps = 0.f, pd = 0.f;
  #pragma unroll
  for (int j=0;j<8;++j){
    float xv = bf2f((ushort)v[j]);
    ps += xv * att_src[lane*8+j];
    pd += xv * att_dst[lane*8+j];
  }
  #pragma unroll
  for (int off=32; off>0; off>>=1){ ps += __shfl_down(ps, off); pd += __shfl_down(pd, off); }
  if (lane == 0){ a_src[row] = ps; a_dst[row] = pd; }
}

// ---------------- per-node segment softmax over CSR edges (16-lane groups) ----------------
__global__ __launch_bounds__(256) void alpha_kernel(const int* __restrict__ row_ptr,
    const int* __restrict__ csr_src, const float* __restrict__ a_src,
    const float* __restrict__ a_dst, float* __restrict__ csr_alpha){
  int gid = blockIdx.x*256 + threadIdx.x;
  int v = gid >> 4, lane = gid & 15;
  if (v >= NNODES) return;
  int p0 = row_ptr[v], p1 = row_ptr[v+1];
  if (p0 >= p1) return;
  float ad = a_dst[v];
  float m = -1e30f;
  for (int p = p0 + lane; p < p1; p += 16){
    float s = 1.f/(1.f + __expf(-(a_src[csr_src[p]] + ad)));
    m = fmaxf(m, s);
  }
  #pragma unroll
  for (int off=8; off>0; off>>=1) m = fmaxf(m, __shfl_xor(m, off));
  float sum = 0.f;
  for (int p = p0 + lane; p < p1; p += 16){
    float s = 1.f/(1.f + __expf(-(a_src[csr_src[p]] + ad)));
    float e = __expf(s - m);
    csr_alpha[p] = e;
    sum += e;
  }
  #pragma unroll
  for (int off=8; off>0; off>>=1) sum += __shfl_xor(sum, off);
  float inv = 1.f/(sum + 1e-16f);
  for (int p = p0 + lane; p < p1; p += 16) csr_alpha[p] *= inv;
}

// ---------------- aggregate: out[v] = elu( sum_e alpha_e * X[src_e] ) ----------------
// 128 threads: two 64-lane halves split the edge list; 16B loads; LDS combine.
__global__ __launch_bounds__(128) void agg_kernel(const ushort* __restrict__ X,
    const int* __restrict__ row_ptr, const int* __restrict__ csr_src,
    const float* __restrict__ csr_alpha, ushort* __restrict__ outb){
  __shared__ float red[64*8];
  int v = blockIdx.x;
  int lane = threadIdx.x & 63;
  int half = threadIdx.x >> 6;
  int p0 = row_ptr[v], p1 = row_ptr[v+1];
  float acc[8] = {0.f,0.f,0.f,0.f,0.f,0.f,0.f,0.f};
  for (int p = p0 + half; p < p1; p += 2){
    int s = csr_src[p];
    float al = csr_alpha[p];
    bf16x8 xv = *(const bf16x8*)(X + (size_t)s*HIDD + lane*8);
    #pragma unroll
    for (int j=0;j<8;++j) acc[j] += al * bf2f((ushort)xv[j]);
  }
  if (half == 1){
    #pragma unroll
    for (int j=0;j<8;++j) red[lane*8+j] = acc[j];
  }
  __syncthreads();
  if (half == 0){
    bf16x8 o;
    #pragma unroll
    for (int j=0;j<8;++j){
      float a = acc[j] + red[lane*8+j];
      a = a > 0.f ? a : __expf(a)-1.f;
      o[j] = (short)f2bf(a);
    }
    *(bf16x8*)(outb + (size_t)v*HIDD + lane*8) = o;
  }
}

// ---------------- h2 = h1 @ W2 (K=512, N=30) ----------------
__global__ __launch_bounds__(256) void mid_kernel(const ushort* __restrict__ h1,
    const ushort* __restrict__ W2tc, float* __restrict__ h2){
  __shared__ ushort h1s[32*512];
  __shared__ ushort w2s[32*512];
  const int t = threadIdx.x;
  const int row0 = blockIdx.x * 32;
  const ushort* g = h1 + (size_t)row0*HIDD;
  #pragma unroll
  for (int it=0; it<8; ++it){
    int ch = t + it*256;
    *(bf16x8*)&h1s[ch*8] = *(const bf16x8*)&g[ch*8];
    *(bf16x8*)&w2s[ch*8] = *(const bf16x8*)&W2tc[ch*8];
  }
  __syncthreads();
  int c = t & 31, rg = t >> 5;
  if (c < ODIM){
    float acc[4] = {0.f,0.f,0.f,0.f};
    for (int k0=0;k0<64;++k0){
      bf16x8 wv = *(const bf16x8*)&w2s[c*512 + k0*8];
      #pragma unroll
      for (int rr=0; rr<4; ++rr){
        bf16x8 hv = *(const bf16x8*)&h1s[(rg*4+rr)*HIDD + k0*8];
        #pragma unroll
        for (int j=0;j<8;++j) acc[rr] += bf2f((ushort)hv[j]) * bf2f((ushort)wv[j]);
      }
    }
    #pragma unroll
    for (int rr=0;rr<4;++rr) h2[(size_t)(row0 + rg*4 + rr)*ODIM + c] = acc[rr];
  }
}

// ---------------- x3 = h2 @ W2^T (K=30, N=512) ----------------
__global__ __launch_bounds__(256) void x3_kernel(const float* __restrict__ h2,
    const ushort* __restrict__ W2p, ushort* __restrict__ x3){
  int gid = blockIdx.x*256 + threadIdx.x;
  int row = gid >> 6, lane = gid & 63;
  if (row >= NNODES) return;
  float h[ODIM];
  #pragma unroll
  for (int ci=0; ci<ODIM; ++ci) h[ci] = h2[(size_t)row*ODIM + ci];
  #pragma unroll
  for (int it=0; it<8; ++it){
    int n = it*64 + lane;
    const ushort* wr = W2p + n*32;
    bf16x8 wvv[4];
    #pragma unroll
    for (int q=0;q<4;++q) wvv[q] = *(const bf16x8*)(wr + q*8);
    float acc = 0.f;
    #pragma unroll
    for (int ci=0; ci<ODIM; ++ci) acc += h[ci]*bf2f((ushort)wvv[ci>>3][ci&7]);
    x3[(size_t)row*HIDD + n] = f2bf(acc);
  }
}

extern "C" void kernel_launch(void* const* d_in, const int* in_sizes, int n_in,
                              void* d_out, int out_size, void* d_ws, size_t ws_size,
                              hipStream_t stream){
  const float* features = (const float*)d_in[0];
  const float* W1 = (const float*)d_in[1];
  const float* W2 = (const float*)d_in[2];
  const float* att_src = (const float*)d_in[3];
  const float* att_dst = (const float*)d_in[4];
  const int* edge = (const int*)d_in[5];
  const int* esrc = edge;
  const int* edst = edge + NEDGES;

  float* h2 = (float*)d_out;                              // [40000][30]
  float* h4 = h2 + (size_t)NNODES*ODIM;                   // [40000][2000]
  char* obase = (char*)h4;                                // 320 MB region, scratch until GEMM4
  ushort* featb = (ushort*)obase;                         // [40000][2048] bf16 = 163.84 MB
  ushort* x1b   = (ushort*)(obase + 163840000);           // [40000][512]  bf16 = 40.96 MB
  ushort* h1b   = (ushort*)(obase + 204800000);
  ushort* x3b   = (ushort*)(obase + 245760000);           // ends at 286.72 MB < 320 MB

  char* wbase = (char*)d_ws;
  size_t o = 0;
  auto walloc = [&](size_t bytes)->void*{ void* p = wbase + o; o += (bytes + 255) & ~(size_t)255; return p; };
  ushort* h3b      = (ushort*)walloc((size_t)NNODES*HIDD*2);
  ushort* W1b      = (ushort*)walloc((size_t)INDIM*HIDD*2);
  ushort* W1t      = (ushort*)walloc((size_t)HIDD*KPAD*2);
  ushort* W2p      = (ushort*)walloc(512*32*2);
  ushort* W2tc     = (ushort*)walloc(32*512*2);
  float*  a_src    = (float*)walloc(NNODES*4);
  float*  a_dst    = (float*)walloc(NNODES*4);
  int*    deg      = (int*)walloc(NNODES*4);
  int*    cursor   = (int*)walloc(NNODES*4);
  int*    row_ptr  = (int*)walloc((NNODES+1)*4);
  int*    csr_src  = (int*)walloc(NEDGES*4);
  float*  csr_alpha= (float*)walloc(NEDGES*4);

  hipMemsetAsync(deg, 0, NNODES*4, stream);
  hipMemsetAsync(cursor, 0, NNODES*4, stream);
  hipMemsetAsync(W1t, 0, (size_t)HIDD*KPAD*2, stream);

  cast_feat_kernel<<<40000, 256, 0, stream>>>(features, featb);
  cast_w1_kernel<<<(INDIM*HIDD+255)/256, 256, 0, stream>>>(W1, W1b, W1t);
  cast_w2_kernel<<<(HIDD*32+255)/256, 256, 0, stream>>>(W2, W2p, W2tc);
  hist_kernel<<<(NEDGES+255)/256, 256, 0, stream>>>(edst, deg);
  scan_kernel<<<1, 1024, 0, stream>>>(deg, row_ptr);
  place_kernel<<<(NEDGES+255)/256, 256, 0, stream>>>(esrc, edst, row_ptr, cursor, csr_src);

  gemm_bt_kernel<ushort><<<dim3(313, 4), 256, 0, stream>>>(featb, W1t, x1b, NNODES, HIDD, KPAD, HIDD);
  a_kernel<<<10000, 256, 0, stream>>>(x1b, att_src, att_dst, a_src, a_dst);
  alpha_kernel<<<2500, 256, 0, stream>>>(row_ptr, csr_src, a_src, a_dst, csr_alpha);
  agg_kernel<<<NNODES, 128, 0, stream>>>(x1b, row_ptr, csr_src, csr_alpha, h1b);
  mid_kernel<<<NNODES/32, 256, 0, stream>>>(h1b, W2tc, h2);
  x3_kernel<<<10000, 256, 0, stream>>>(h2, W2p, x3b);
  agg_kernel<<<NNODES, 128, 0, stream>>>(x3b, row_ptr, csr_src, csr_alpha, h3b);
  gemm_bt_kernel<float><<<dim3(313, 16), 256, 0, stream>>>(h3b, W1b, h4, NNODES, INDIM, HIDD, INDIM);
}

// Round 3
// 732.499 us; speedup vs baseline: 1.1175x; 1.0588x over previous
//
#include <hip/hip_runtime.h>
#include <cstdint>

#define NNODES 40000
#define INDIM 2000
#define HIDD 512
#define ODIM 30
#define NEDGES 400000
#define KPAD 2048

typedef short bf16x8 __attribute__((ext_vector_type(8)));
typedef float f32x4 __attribute__((ext_vector_type(4)));

__device__ __forceinline__ float bf2f(ushort u){ union{unsigned int i; float f;} x; x.i = ((unsigned int)u)<<16; return x.f; }
__device__ __forceinline__ ushort f2bf(float v){ union{float f; unsigned int u;} x; x.f=v; unsigned int r = x.u + 0x7fffu + ((x.u>>16)&1u); return (ushort)(r>>16); }

// ---------------- casts ----------------
__global__ __launch_bounds__(256) void cast_feat_kernel(const float* __restrict__ src, ushort* __restrict__ dstb){
  int c = blockIdx.x*256 + threadIdx.x;          // chunk of 8 elems; 40000*256 chunks
  int row = c >> 8, kc = c & 255;
  bf16x8 o;
  if (kc < INDIM/8) {
    const float* p = src + (size_t)row*INDIM + kc*8;
    #pragma unroll
    for (int j=0;j<8;++j) o[j] = (short)f2bf(p[j]);
  } else {
    #pragma unroll
    for (int j=0;j<8;++j) o[j] = 0;
  }
  *(bf16x8*)(dstb + (size_t)row*KPAD + kc*8) = o;
}

__global__ __launch_bounds__(256) void cast_w1_kernel(const float* __restrict__ W1, ushort* __restrict__ W1b, ushort* __restrict__ W1t){
  int idx = blockIdx.x*256 + threadIdx.x;        // 2000*512
  if (idx >= INDIM*HIDD) return;
  int r = idx >> 9, c = idx & 511;
  ushort b = f2bf(W1[idx]);
  W1b[idx] = b;
  W1t[(size_t)c*KPAD + r] = b;                   // pad cols [2000,2048) pre-zeroed
}

__global__ __launch_bounds__(256) void cast_w2_kernel(const float* __restrict__ W2, ushort* __restrict__ W2p, ushort* __restrict__ W2tc){
  int idx = blockIdx.x*256 + threadIdx.x;        // 512*32 padded
  if (idx >= HIDD*32) return;
  int k = idx >> 5, c = idx & 31;
  float val = (c < ODIM) ? W2[k*ODIM + c] : 0.f;
  ushort b = f2bf(val);
  W2p[k*32 + c] = b;                             // [512][32] k-major
  W2tc[c*HIDD + k] = b;                          // [32][512] c-major (rows 30,31 zero)
}

// ---------------- CSR build ----------------
__global__ __launch_bounds__(256) void hist_kernel(const int* __restrict__ dst, int* __restrict__ deg){
  int e = blockIdx.x*256 + threadIdx.x;
  if (e < NEDGES) atomicAdd(&deg[dst[e]], 1);
}

// one block, 1024 threads; each thread scans 40 elements (int4 loads), one block scan of partials.
__global__ __launch_bounds__(1024) void scan_kernel(const int* __restrict__ deg, int* __restrict__ row_ptr){
  __shared__ int part[1024];
  const int t = threadIdx.x;
  const int base = t * 40;
  int v[40];
  int s = 0;
  if (base < NNODES) {                 // NNODES%40==0: in-range threads fully in-range
    const int4* dp = (const int4*)(deg + base);
    #pragma unroll
    for (int j=0;j<10;++j){
      int4 d = dp[j];
      v[4*j+0] = s; s += d.x;
      v[4*j+1] = s; s += d.y;
      v[4*j+2] = s; s += d.z;
      v[4*j+3] = s; s += d.w;
    }
  } else {
    #pragma unroll
    for (int j=0;j<40;++j) v[j] = 0;
  }
  part[t] = s;
  __syncthreads();
  #pragma unroll
  for (int off=1; off<1024; off<<=1){
    int x = (t >= off) ? part[t-off] : 0;
    __syncthreads();
    part[t] += x;
    __syncthreads();
  }
  int offset = (t > 0) ? part[t-1] : 0;
  #pragma unroll
  for (int j=0;j<40;++j){
    int i = base + j;
    if (i <= NNODES) row_ptr[i] = offset + v[j];
  }
}

__global__ __launch_bounds__(256) void place_kernel(const int* __restrict__ src, const int* __restrict__ dst,
    const int* __restrict__ row_ptr, int* __restrict__ cursor, int* __restrict__ csr_src){
  int e = blockIdx.x*256 + threadIdx.x;
  if (e >= NEDGES) return;
  int d = dst[e];
  int pos = row_ptr[d] + atomicAdd(&cursor[d], 1);
  csr_src[pos] = src[e];
}

// ---------------- bf16 MFMA GEMM, Bt form: C[M][N] = A[M][K] * Bt[N][K]^T ----------------
// Epilogue goes through LDS for coalesced 16B stores.
template<typename OutT>
__global__ __launch_bounds__(256, 2) void gemm_bt_kernel(
    const ushort* __restrict__ A, const ushort* __restrict__ Bt,
    OutT* __restrict__ C, int M, int N, int K, int ldc)
{
  __shared__ __align__(16) char smem[35072];
  ushort* As = (ushort*)smem;                    // [1024] chunks of 8 = 16KB
  ushort* Bs = As + 128*64;                      // 16KB
  const int tid = threadIdx.x;
  const int lane = tid & 63;
  const int w = tid >> 6;
  const int wm = w >> 1, wn = w & 1;
  const int row0 = blockIdx.x * 128;
  const int col0 = blockIdx.y * 128;
  f32x4 acc[4][4] = {};

  for (int k0 = 0; k0 < K; k0 += 64) {
    #pragma unroll
    for (int it = 0; it < 4; ++it) {
      int ch = tid + it*256;                 // 0..1023 chunks of 16B
      int r = ch >> 3, k8 = (ch & 7) * 8;
      int ra = row0 + r; ra = ra < M ? ra : M-1;
      int rb = col0 + r; rb = rb < N ? rb : N-1;
      __builtin_amdgcn_global_load_lds(
        (const __attribute__((address_space(1))) unsigned int*)(A + (size_t)ra*K + k0 + k8),
        (__attribute__((address_space(3))) unsigned int*)(&As[ch*8]), 16, 0, 0);
      __builtin_amdgcn_global_load_lds(
        (const __attribute__((address_space(1))) unsigned int*)(Bt + (size_t)rb*K + k0 + k8),
        (__attribute__((address_space(3))) unsigned int*)(&Bs[ch*8]), 16, 0, 0);
    }
    __syncthreads();
    #pragma unroll
    for (int kk = 0; kk < 2; ++kk) {
      bf16x8 af[4], bfr[4];
      const int ko = kk*32 + (lane>>4)*8;
      #pragma unroll
      for (int i=0;i<4;++i) af[i] = *(const bf16x8*)&As[(wm*64 + i*16 + (lane&15))*64 + ko];
      #pragma unroll
      for (int j=0;j<4;++j) bfr[j] = *(const bf16x8*)&Bs[(wn*64 + j*16 + (lane&15))*64 + ko];
      #pragma unroll
      for (int i=0;i<4;++i)
        #pragma unroll
        for (int j=0;j<4;++j)
          acc[i][j] = __builtin_amdgcn_mfma_f32_16x16x32_bf16(af[i], bfr[j], acc[i][j], 0, 0, 0);
    }
    __syncthreads();
  }

  if constexpr (sizeof(OutT)==2) {
    // bf16 out: stage full 128x128 bf16 tile in LDS (stride 136), copy coalesced.
    ushort* cs = (ushort*)smem;
    const int r0 = wm*64 + ((lane>>4)<<2);
    const int c0l = wn*64 + (lane&15);
    #pragma unroll
    for (int i=0;i<4;++i)
      #pragma unroll
      for (int j=0;j<4;++j)
        #pragma unroll
        for (int reg=0;reg<4;++reg)
          cs[(r0 + i*16 + reg)*136 + c0l + j*16] = f2bf(acc[i][j][reg]);
    __syncthreads();
    #pragma unroll
    for (int it=0; it<8; ++it){
      int ch = tid + it*256;                 // 2048 chunks: 128 rows x 16 chunks
      int r = ch >> 4, c8 = (ch & 15) * 8;
      int gr = row0 + r;
      if (gr < M) *(bf16x8*)&((ushort*)C)[(size_t)gr*ldc + col0 + c8] = *(const bf16x8*)&cs[r*136 + c8];
    }
  } else {
    // f32 out: two passes of 64 rows (stride 132), copy coalesced dwordx4.
    float* cf = (float*)smem;
    #pragma unroll
    for (int p=0;p<2;++p){
      if (wm == p){
        #pragma unroll
        for (int i=0;i<4;++i)
          #pragma unroll
          for (int j=0;j<4;++j)
            #pragma unroll
            for (int reg=0;reg<4;++reg)
              cf[(i*16 + ((lane>>4)<<2) + reg)*132 + wn*64 + (lane&15) + j*16] = acc[i][j][reg];
      }
      __syncthreads();
      #pragma unroll
      for (int it=0; it<8; ++it){
        int ch = tid + it*256;               // 2048 chunks: 64 rows x 32 chunks
        int r = ch >> 5, c4 = (ch & 31) * 4;
        int gr = row0 + p*64 + r, gc = col0 + c4;
        if (gr < M && gc + 4 <= N) *(f32x4*)&((float*)C)[(size_t)gr*ldc + gc] = *(const f32x4*)&cf[r*132 + c4];
      }
      __syncthreads();
    }
  }
}

// ---------------- a_src/a_dst: per-row dot with att vectors ----------------
__global__ __launch_bounds__(256) void a_kernel(const ushort* __restrict__ x1,
    const float* __restrict__ att_src, const float* __restrict__ att_dst,
    float* __restrict__ a_src, float* __restrict__ a_dst){
  int gid = blockIdx.x*256 + threadIdx.x;
  int row = gid >> 6, lane = gid & 63;
  if (row >= NNODES) return;
  bf16x8 v = *(const bf16x8*)(x1 + (size_t)row*HIDD + lane*8);
  float ps = 0.f, pd = 0.f;
  #pragma unroll
  for (int j=0;j<8;++j){
    float xv = bf2f((ushort)v[j]);
    ps += xv * att_src[lane*8+j];
    pd += xv * att_dst[lane*8+j];
  }
  #pragma unroll
  for (int off=32; off>0; off>>=1){ ps += __shfl_down(ps, off); pd += __shfl_down(pd, off); }
  if (lane == 0){ a_src[row] = ps; a_dst[row] = pd; }
}

// ---------------- per-node segment softmax over CSR edges (16-lane groups) ----------------
__global__ __launch_bounds__(256) void alpha_kernel(const int* __restrict__ row_ptr,
    const int* __restrict__ csr_src, const float* __restrict__ a_src,
    const float* __restrict__ a_dst, float* __restrict__ csr_alpha){
  int gid = blockIdx.x*256 + threadIdx.x;
  int v = gid >> 4, lane = gid & 15;
  if (v >= NNODES) return;
  int p0 = row_ptr[v], p1 = row_ptr[v+1];
  if (p0 >= p1) return;
  float ad = a_dst[v];
  float m = -1e30f;
  for (int p = p0 + lane; p < p1; p += 16){
    float s = 1.f/(1.f + __expf(-(a_src[csr_src[p]] + ad)));
    m = fmaxf(m, s);
  }
  #pragma unroll
  for (int off=8; off>0; off>>=1) m = fmaxf(m, __shfl_xor(m, off));
  float sum = 0.f;
  for (int p = p0 + lane; p < p1; p += 16){
    float s = 1.f/(1.f + __expf(-(a_src[csr_src[p]] + ad)));
    float e = __expf(s - m);
    csr_alpha[p] = e;
    sum += e;
  }
  #pragma unroll
  for (int off=8; off>0; off>>=1) sum += __shfl_xor(sum, off);
  float inv = 1.f/(sum + 1e-16f);
  for (int p = p0 + lane; p < p1; p += 16) csr_alpha[p] *= inv;
}

// ---------------- conv1 aggregate: out[v] = elu( sum_e alpha_e * X[src_e] ), 512-wide ----------------
// 256 threads: four 64-lane quarters split the edge list; 16B loads; LDS combine.
__global__ __launch_bounds__(256) void agg_kernel(const ushort* __restrict__ X,
    const int* __restrict__ row_ptr, const int* __restrict__ csr_src,
    const float* __restrict__ csr_alpha, ushort* __restrict__ outb){
  __shared__ float red[3][64*8];
  int v = blockIdx.x;
  int lane = threadIdx.x & 63;
  int q = threadIdx.x >> 6;
  int p0 = row_ptr[v], p1 = row_ptr[v+1];
  float acc[8] = {0.f,0.f,0.f,0.f,0.f,0.f,0.f,0.f};
  for (int p = p0 + q; p < p1; p += 4){
    int s = csr_src[p];
    float al = csr_alpha[p];
    bf16x8 xv = *(const bf16x8*)(X + (size_t)s*HIDD + lane*8);
    #pragma unroll
    for (int j=0;j<8;++j) acc[j] += al * bf2f((ushort)xv[j]);
  }
  if (q > 0){
    #pragma unroll
    for (int j=0;j<8;++j) red[q-1][lane*8+j] = acc[j];
  }
  __syncthreads();
  if (q == 0){
    bf16x8 o;
    #pragma unroll
    for (int j=0;j<8;++j){
      float a = acc[j] + red[0][lane*8+j] + red[1][lane*8+j] + red[2][lane*8+j];
      a = a > 0.f ? a : __expf(a)-1.f;
      o[j] = (short)f2bf(a);
    }
    *(bf16x8*)(outb + (size_t)v*HIDD + lane*8) = o;
  }
}

// ---------------- h2 = h1 @ W2 (K=512, N=30) ----------------
__global__ __launch_bounds__(256) void mid_kernel(const ushort* __restrict__ h1,
    const ushort* __restrict__ W2tc, float* __restrict__ h2){
  __shared__ ushort h1s[32*512];
  __shared__ ushort w2s[32*512];
  const int t = threadIdx.x;
  const int row0 = blockIdx.x * 32;
  const ushort* g = h1 + (size_t)row0*HIDD;
  #pragma unroll
  for (int it=0; it<8; ++it){
    int ch = t + it*256;
    *(bf16x8*)&h1s[ch*8] = *(const bf16x8*)&g[ch*8];
    *(bf16x8*)&w2s[ch*8] = *(const bf16x8*)&W2tc[ch*8];
  }
  __syncthreads();
  int c = t & 31, rg = t >> 5;
  if (c < ODIM){
    float acc[4] = {0.f,0.f,0.f,0.f};
    for (int k0=0;k0<64;++k0){
      bf16x8 wv = *(const bf16x8*)&w2s[c*512 + k0*8];
      #pragma unroll
      for (int rr=0; rr<4; ++rr){
        bf16x8 hv = *(const bf16x8*)&h1s[(rg*4+rr)*HIDD + k0*8];
        #pragma unroll
        for (int j=0;j<8;++j) acc[rr] += bf2f((ushort)hv[j]) * bf2f((ushort)wv[j]);
      }
    }
    #pragma unroll
    for (int rr=0;rr<4;++rr) h2[(size_t)(row0 + rg*4 + rr)*ODIM + c] = acc[rr];
  }
}

// ---------------- conv3 aggregate on 30-dim h2: g[v] = sum_e alpha_e * h2[src_e] ----------------
// (propagate is linear: agg(h2 @ W2^T) == agg(h2) @ W2^T)
__global__ __launch_bounds__(256) void agg30_kernel(const float* __restrict__ h2,
    const int* __restrict__ row_ptr, const int* __restrict__ csr_src,
    const float* __restrict__ csr_alpha, float* __restrict__ g){
  int gid = blockIdx.x*256 + threadIdx.x;
  int v = gid >> 5, lane = gid & 31;
  if (v >= NNODES) return;
  int p0 = row_ptr[v], p1 = row_ptr[v+1];
  float acc = 0.f;
  if (lane < ODIM){
    for (int p = p0; p < p1; ++p){
      acc += csr_alpha[p] * h2[(size_t)csr_src[p]*ODIM + lane];
    }
  }
  g[(size_t)v*32 + lane] = acc;
}

// ---------------- h3 = elu( g @ W2^T ) (K=30, N=512), bf16 out ----------------
__global__ __launch_bounds__(256) void g2h3_kernel(const float* __restrict__ g,
    const ushort* __restrict__ W2p, ushort* __restrict__ h3){
  int gid = blockIdx.x*256 + threadIdx.x;
  int row = gid >> 6, lane = gid & 63;
  if (row >= NNODES) return;
  float h[ODIM];
  #pragma unroll
  for (int ci=0; ci<ODIM; ++ci) h[ci] = g[(size_t)row*32 + ci];
  #pragma unroll
  for (int it=0; it<8; ++it){
    int n = it*64 + lane;
    const ushort* wr = W2p + n*32;
    bf16x8 wvv[4];
    #pragma unroll
    for (int q=0;q<4;++q) wvv[q] = *(const bf16x8*)(wr + q*8);
    float acc = 0.f;
    #pragma unroll
    for (int ci=0; ci<ODIM; ++ci) acc += h[ci]*bf2f((ushort)wvv[ci>>3][ci&7]);
    acc = acc > 0.f ? acc : __expf(acc)-1.f;
    h3[(size_t)row*HIDD + n] = f2bf(acc);
  }
}

extern "C" void kernel_launch(void* const* d_in, const int* in_sizes, int n_in,
                              void* d_out, int out_size, void* d_ws, size_t ws_size,
                              hipStream_t stream){
  const float* features = (const float*)d_in[0];
  const float* W1 = (const float*)d_in[1];
  const float* W2 = (const float*)d_in[2];
  const float* att_src = (const float*)d_in[3];
  const float* att_dst = (const float*)d_in[4];
  const int* edge = (const int*)d_in[5];
  const int* esrc = edge;
  const int* edst = edge + NEDGES;

  float* h2 = (float*)d_out;                              // [40000][30]
  float* h4 = h2 + (size_t)NNODES*ODIM;                   // [40000][2000]
  char* obase = (char*)h4;                                // 320 MB region, scratch until GEMM4
  ushort* featb = (ushort*)obase;                         // [40000][2048] bf16 = 163.84 MB
  ushort* x1b   = (ushort*)(obase + 163840000);           // [40000][512]  bf16 = 40.96 MB
  ushort* h1b   = (ushort*)(obase + 204800000);           // ends at 245.76 MB < 320 MB

  char* wbase = (char*)d_ws;
  size_t o = 0;
  auto walloc = [&](size_t bytes)->void*{ void* p = wbase + o; o += (bytes + 255) & ~(size_t)255; return p; };
  ushort* h3b      = (ushort*)walloc((size_t)NNODES*HIDD*2);
  ushort* W1b      = (ushort*)walloc((size_t)INDIM*HIDD*2);
  ushort* W1t      = (ushort*)walloc((size_t)HIDD*KPAD*2);
  ushort* W2p      = (ushort*)walloc(512*32*2);
  ushort* W2tc     = (ushort*)walloc(32*512*2);
  float*  a_src    = (float*)walloc(NNODES*4);
  float*  a_dst    = (float*)walloc(NNODES*4);
  int*    deg      = (int*)walloc(NNODES*4);
  int*    cursor   = (int*)walloc(NNODES*4);
  int*    row_ptr  = (int*)walloc((NNODES+1)*4);
  int*    csr_src  = (int*)walloc(NEDGES*4);
  float*  csr_alpha= (float*)walloc(NEDGES*4);
  float*  gbuf     = (float*)walloc((size_t)NNODES*32*4);

  hipMemsetAsync(deg, 0, NNODES*4, stream);
  hipMemsetAsync(cursor, 0, NNODES*4, stream);
  hipMemsetAsync(W1t, 0, (size_t)HIDD*KPAD*2, stream);

  cast_feat_kernel<<<40000, 256, 0, stream>>>(features, featb);
  cast_w1_kernel<<<(INDIM*HIDD+255)/256, 256, 0, stream>>>(W1, W1b, W1t);
  cast_w2_kernel<<<(HIDD*32+255)/256, 256, 0, stream>>>(W2, W2p, W2tc);
  hist_kernel<<<(NEDGES+255)/256, 256, 0, stream>>>(edst, deg);
  scan_kernel<<<1, 1024, 0, stream>>>(deg, row_ptr);
  place_kernel<<<(NEDGES+255)/256, 256, 0, stream>>>(esrc, edst, row_ptr, cursor, csr_src);

  gemm_bt_kernel<ushort><<<dim3(313, 4), 256, 0, stream>>>(featb, W1t, x1b, NNODES, HIDD, KPAD, HIDD);
  a_kernel<<<10000, 256, 0, stream>>>(x1b, att_src, att_dst, a_src, a_dst);
  alpha_kernel<<<2500, 256, 0, stream>>>(row_ptr, csr_src, a_src, a_dst, csr_alpha);
  agg_kernel<<<NNODES, 256, 0, stream>>>(x1b, row_ptr, csr_src, csr_alpha, h1b);
  mid_kernel<<<NNODES/32, 256, 0, stream>>>(h1b, W2tc, h2);
  agg30_kernel<<<NNODES*32/256, 256, 0, stream>>>(h2, row_ptr, csr_src, csr_alpha, gbuf);
  g2h3_kernel<<<10000, 256, 0, stream>>>(gbuf, W2p, h3b);
  gemm_bt_kernel<float><<<dim3(313, 16), 256, 0, stream>>>(h3b, W1b, h4, NNODES, INDIM, HIDD, INDIM);
}

// Round 4
// 679.322 us; speedup vs baseline: 1.2050x; 1.0783x over previous
//
#include <hip/hip_runtime.h>
#include <cstdint>

#define NNODES 40000
#define INDIM 2000
#define HIDD 512
#define ODIM 30
#define NEDGES 400000
#define KPAD 2048

typedef short bf16x8 __attribute__((ext_vector_type(8)));
typedef float f32x4 __attribute__((ext_vector_type(4)));

__device__ __forceinline__ float bf2f(ushort u){ union{unsigned int i; float f;} x; x.i = ((unsigned int)u)<<16; return x.f; }
__device__ __forceinline__ ushort f2bf(float v){ union{float f; unsigned int u;} x; x.f=v; unsigned int r = x.u + 0x7fffu + ((x.u>>16)&1u); return (ushort)(r>>16); }

// ---------------- casts ----------------
__global__ __launch_bounds__(256) void cast_feat_kernel(const float* __restrict__ src, ushort* __restrict__ dstb){
  int c = blockIdx.x*256 + threadIdx.x;
  int row = c >> 8, kc = c & 255;
  bf16x8 o;
  if (kc < INDIM/8) {
    const float* p = src + (size_t)row*INDIM + kc*8;
    #pragma unroll
    for (int j=0;j<8;++j) o[j] = (short)f2bf(p[j]);
  } else {
    #pragma unroll
    for (int j=0;j<8;++j) o[j] = 0;
  }
  *(bf16x8*)(dstb + (size_t)row*KPAD + kc*8) = o;
}

__global__ __launch_bounds__(256) void cast_w1_kernel(const float* __restrict__ W1, ushort* __restrict__ W1b, ushort* __restrict__ W1t){
  int idx = blockIdx.x*256 + threadIdx.x;
  if (idx >= INDIM*HIDD) return;
  int r = idx >> 9, c = idx & 511;
  ushort b = f2bf(W1[idx]);
  W1b[idx] = b;
  W1t[(size_t)c*KPAD + r] = b;
}

__global__ __launch_bounds__(256) void cast_w2_kernel(const float* __restrict__ W2, ushort* __restrict__ W2p, ushort* __restrict__ W2tc){
  int idx = blockIdx.x*256 + threadIdx.x;
  if (idx >= HIDD*32) return;
  int k = idx >> 5, c = idx & 31;
  float val = (c < ODIM) ? W2[k*ODIM + c] : 0.f;
  ushort b = f2bf(val);
  W2p[k*32 + c] = b;
  W2tc[c*HIDD + k] = b;
}

// ---------------- CSR build ----------------
__global__ __launch_bounds__(256) void hist_kernel(const int* __restrict__ dst, int* __restrict__ deg){
  int e = blockIdx.x*256 + threadIdx.x;
  if (e < NEDGES) atomicAdd(&deg[dst[e]], 1);
}

__global__ __launch_bounds__(1024) void scan_kernel(const int* __restrict__ deg, int* __restrict__ row_ptr){
  __shared__ int part[1024];
  const int t = threadIdx.x;
  const int base = t * 40;
  int v[40];
  int s = 0;
  if (base < NNODES) {
    const int4* dp = (const int4*)(deg + base);
    #pragma unroll
    for (int j=0;j<10;++j){
      int4 d = dp[j];
      v[4*j+0] = s; s += d.x;
      v[4*j+1] = s; s += d.y;
      v[4*j+2] = s; s += d.z;
      v[4*j+3] = s; s += d.w;
    }
  } else {
    #pragma unroll
    for (int j=0;j<40;++j) v[j] = 0;
  }
  part[t] = s;
  __syncthreads();
  #pragma unroll
  for (int off=1; off<1024; off<<=1){
    int x = (t >= off) ? part[t-off] : 0;
    __syncthreads();
    part[t] += x;
    __syncthreads();
  }
  int offset = (t > 0) ? part[t-1] : 0;
  #pragma unroll
  for (int j=0;j<40;++j){
    int i = base + j;
    if (i <= NNODES) row_ptr[i] = offset + v[j];
  }
}

__global__ __launch_bounds__(256) void place_kernel(const int* __restrict__ src, const int* __restrict__ dst,
    const int* __restrict__ row_ptr, int* __restrict__ cursor, int* __restrict__ csr_src){
  int e = blockIdx.x*256 + threadIdx.x;
  if (e >= NEDGES) return;
  int d = dst[e];
  int pos = row_ptr[d] + atomicAdd(&cursor[d], 1);
  csr_src[pos] = src[e];
}

// ---------------- 256x256 8-phase bf16 MFMA GEMM, Bt form: C = A[M][K] * Bt[N][K]^T --------
// 512 threads = 8 waves (2M x 4N), per-wave 128x64 output, BK=64, double-buffered 128KiB LDS,
// XOR-swizzled LDS (elem ^= (row&7)<<3) with pre-swizzled global source, counted vmcnt(4),
// raw s_barrier (no vmcnt(0) drain in K-loop), setprio around MFMA clusters.
#define P_MID  asm volatile("" ::: "memory"); __builtin_amdgcn_s_barrier(); \
               asm volatile("s_waitcnt lgkmcnt(0)" ::: "memory"); \
               __builtin_amdgcn_sched_barrier(0); __builtin_amdgcn_s_setprio(1);
#define P_END  __builtin_amdgcn_s_setprio(0); asm volatile("" ::: "memory"); \
               __builtin_amdgcn_s_barrier(); __builtin_amdgcn_sched_barrier(0);
#define P_ENDW __builtin_amdgcn_s_setprio(0); \
               asm volatile("s_waitcnt vmcnt(4)" ::: "memory"); \
               asm volatile("" ::: "memory"); __builtin_amdgcn_s_barrier(); \
               __builtin_amdgcn_sched_barrier(0);

template<typename OutT>
__global__ __launch_bounds__(512, 2) void gemm8_kernel(
    const ushort* __restrict__ A, const ushort* __restrict__ Bt,
    OutT* __restrict__ C, int M, int N, int K, int ldc)
{
  __shared__ __align__(16) char smem[131072];
  ushort* Al = (ushort*)smem;                // [2][256][64]
  ushort* Bl = (ushort*)(smem + 65536);      // [2][256][64]
  const int tid = threadIdx.x;
  const int lane = tid & 63;
  const int w = tid >> 6;
  const int wm = w >> 2, wn = w & 3;         // 2M x 4N
  const int row0 = blockIdx.y * 256;
  const int col0 = blockIdx.x * 256;
  const int NT = K >> 6;

  f32x4 acc[8][4] = {};
  bf16x8 a[4][2], b[4][2];

  // stage one half-tile (2 x global_load_lds per thread) with pre-swizzled source
  auto stage = [&](bool isA, int kt, int h){
    const ushort* G = isA ? A : Bt;
    int base = isA ? row0 : col0;
    int lim  = isA ? M : N;
    ushort* L = (isA ? Al : Bl) + ((kt & 1) << 14);
    if (kt >= NT) kt -= NT;
    #pragma unroll
    for (int it = 0; it < 2; ++it){
      int ch = tid + (it << 9);            // 0..1023
      int rl = (h << 7) + (ch >> 3);       // row in tile
      int cs = ch & 7;                     // 16B slot
      int gr = base + rl; gr = gr < lim ? gr : lim - 1;
      int gc = (kt << 6) + ((cs ^ (rl & 7)) << 3);
      __builtin_amdgcn_global_load_lds(
        (const __attribute__((address_space(1))) unsigned int*)(G + (size_t)gr*K + gc),
        (__attribute__((address_space(3))) unsigned int*)(L + rl*64 + cs*8), 16, 0, 0);
    }
  };
  auto lda = [&](int buf, int mf, int kk) -> bf16x8 {
    int rl = wm*128 + mf*16 + (lane & 15);
    int ko = kk*32 + ((lane >> 4) << 3);
    return *(const bf16x8*)&Al[(buf << 14) + rl*64 + (ko ^ ((rl & 7) << 3))];
  };
  auto ldb = [&](int buf, int nf, int kk) -> bf16x8 {
    int rl = wn*64 + nf*16 + (lane & 15);
    int ko = kk*32 + ((lane >> 4) << 3);
    return *(const bf16x8*)&Bl[(buf << 14) + rl*64 + (ko ^ ((rl & 7) << 3))];
  };
  auto mfma_q = [&](int mbase, int nbase){
    #pragma unroll
    for (int i=0;i<4;++i)
      #pragma unroll
      for (int j=0;j<2;++j)
        #pragma unroll
        for (int kk=0;kk<2;++kk)
          acc[mbase+i][nbase+j] = __builtin_amdgcn_mfma_f32_16x16x32_bf16(
              a[i][kk], b[nbase+j][kk], acc[mbase+i][nbase+j], 0, 0, 0);
  };

  // prologue: K0.B, K0.A fully; K1.B — then vmcnt(4) leaves only K1.B outstanding
  stage(false, 0, 0); stage(false, 0, 1);
  stage(true , 0, 0); stage(true , 0, 1);
  stage(false, 1, 0); stage(false, 1, 1);
  asm volatile("s_waitcnt vmcnt(4)" ::: "memory");
  asm volatile("" ::: "memory");
  __builtin_amdgcn_s_barrier();
  __builtin_amdgcn_sched_barrier(0);

  const int NT2 = NT >> 1;
  for (int t = 0; t < NT2; ++t){
    const int kt0 = 2*t, kt1 = 2*t + 1;
    // P1: read A0-3,B0-1 of buf0; stage A(kt1) h0
    #pragma unroll
    for (int i=0;i<4;++i){ a[i][0]=lda(0,i,0); a[i][1]=lda(0,i,1); }
    #pragma unroll
    for (int j=0;j<2;++j){ b[j][0]=ldb(0,j,0); b[j][1]=ldb(0,j,1); }
    stage(true, kt1, 0);
    P_MID; mfma_q(0,0); P_END;
    // P2: read B2-3 of buf0; stage A(kt1) h1
    #pragma unroll
    for (int j=2;j<4;++j){ b[j][0]=ldb(0,j,0); b[j][1]=ldb(0,j,1); }
    stage(true, kt1, 1);
    P_MID; mfma_q(0,2); P_END;
    // P3: read A4-7 of buf0; stage B(kt0+2) h0
    #pragma unroll
    for (int i=0;i<4;++i){ a[i][0]=lda(0,4+i,0); a[i][1]=lda(0,4+i,1); }
    stage(false, kt0+2, 0);
    P_MID; mfma_q(4,0); P_END;
    // P4: stage B(kt0+2) h1; vmcnt(4) publishes buf1 (A from P1/P2, B from prev P7/P8)
    stage(false, kt0+2, 1);
    P_MID; mfma_q(4,2); P_ENDW;
    // P5: read A0-3,B0-1 of buf1; stage A(kt0+2) h0
    #pragma unroll
    for (int i=0;i<4;++i){ a[i][0]=lda(1,i,0); a[i][1]=lda(1,i,1); }
    #pragma unroll
    for (int j=0;j<2;++j){ b[j][0]=ldb(1,j,0); b[j][1]=ldb(1,j,1); }
    stage(true, kt0+2, 0);
    P_MID; mfma_q(0,0); P_END;
    // P6: read B2-3 of buf1; stage A(kt0+2) h1
    #pragma unroll
    for (int j=2;j<4;++j){ b[j][0]=ldb(1,j,0); b[j][1]=ldb(1,j,1); }
    stage(true, kt0+2, 1);
    P_MID; mfma_q(0,2); P_END;
    // P7: read A4-7 of buf1; stage B(kt1+2) h0
    #pragma unroll
    for (int i=0;i<4;++i){ a[i][0]=lda(1,4+i,0); a[i][1]=lda(1,4+i,1); }
    stage(false, kt1+2, 0);
    P_MID; mfma_q(4,0); P_END;
    // P8: stage B(kt1+2) h1; vmcnt(4) publishes buf0 (B from P3/P4, A from P5/P6)
    stage(false, kt1+2, 1);
    P_MID; mfma_q(4,2); P_ENDW;
  }

  // drain all dummy stages before reusing LDS
  asm volatile("s_waitcnt vmcnt(0)" ::: "memory");
  __syncthreads();

  if constexpr (sizeof(OutT)==2) {
    ushort* cs = (ushort*)smem;            // [128][264]
    #pragma unroll
    for (int p=0;p<2;++p){
      if (wm == p){
        #pragma unroll
        for (int mf=0;mf<8;++mf)
          #pragma unroll
          for (int nf=0;nf<4;++nf)
            #pragma unroll
            for (int reg=0;reg<4;++reg)
              cs[(mf*16 + ((lane>>4)<<2) + reg)*264 + wn*64 + nf*16 + (lane&15)] = f2bf(acc[mf][nf][reg]);
      }
      __syncthreads();
      #pragma unroll
      for (int it=0; it<8; ++it){
        int ch = tid + it*512;             // 4096 = 128 rows x 32 chunks
        int r = ch >> 5, c8 = (ch & 31) * 8;
        int gr = row0 + p*128 + r;
        if (gr < M && col0 + c8 + 8 <= N)
          *(bf16x8*)&((ushort*)C)[(size_t)gr*ldc + col0 + c8] = *(const bf16x8*)&cs[r*264 + c8];
      }
      __syncthreads();
    }
  } else {
    float* cf = (float*)smem;              // [64][260]
    #pragma unroll
    for (int p=0;p<4;++p){
      if (wm == (p>>1)){
        int mh = (p & 1) * 4;
        #pragma unroll
        for (int i=0;i<4;++i)
          #pragma unroll
          for (int nf=0;nf<4;++nf)
            #pragma unroll
            for (int reg=0;reg<4;++reg)
              cf[(i*16 + ((lane>>4)<<2) + reg)*260 + wn*64 + nf*16 + (lane&15)] = acc[mh+i][nf][reg];
      }
      __syncthreads();
      #pragma unroll
      for (int it=0; it<8; ++it){
        int ch = tid + it*512;             // 4096 = 64 rows x 64 chunks
        int r = ch >> 6, c4 = (ch & 63) * 4;
        int gr = row0 + p*64 + r, gc = col0 + c4;
        if (gr < M && gc + 4 <= N)
          *(f32x4*)&((float*)C)[(size_t)gr*ldc + gc] = *(const f32x4*)&cf[r*260 + c4];
      }
      __syncthreads();
    }
  }
}

// ---------------- a_src/a_dst ----------------
__global__ __launch_bounds__(256) void a_kernel(const ushort* __restrict__ x1,
    const float* __restrict__ att_src, const float* __restrict__ att_dst,
    float* __restrict__ a_src, float* __restrict__ a_dst){
  int gid = blockIdx.x*256 + threadIdx.x;
  int row = gid >> 6, lane = gid & 63;
  if (row >= NNODES) return;
  bf16x8 v = *(const bf16x8*)(x1 + (size_t)row*HIDD + lane*8);
  float ps = 0.f, pd = 0.f;
  #pragma unroll
  for (int j=0;j<8;++j){
    float xv = bf2f((ushort)v[j]);
    ps += xv * att_src[lane*8+j];
    pd += xv * att_dst[lane*8+j];
  }
  #pragma unroll
  for (int off=32; off>0; off>>=1){ ps += __shfl_down(ps, off); pd += __shfl_down(pd, off); }
  if (lane == 0){ a_src[row] = ps; a_dst[row] = pd; }
}

// ---------------- per-node segment softmax (16-lane groups) ----------------
__global__ __launch_bounds__(256) void alpha_kernel(const int* __restrict__ row_ptr,
    const int* __restrict__ csr_src, const float* __restrict__ a_src,
    const float* __restrict__ a_dst, float* __restrict__ csr_alpha){
  int gid = blockIdx.x*256 + threadIdx.x;
  int v = gid >> 4, lane = gid & 15;
  if (v >= NNODES) return;
  int p0 = row_ptr[v], p1 = row_ptr[v+1];
  if (p0 >= p1) return;
  float ad = a_dst[v];
  float m = -1e30f;
  for (int p = p0 + lane; p < p1; p += 16){
    float s = 1.f/(1.f + __expf(-(a_src[csr_src[p]] + ad)));
    m = fmaxf(m, s);
  }
  #pragma unroll
  for (int off=8; off>0; off>>=1) m = fmaxf(m, __shfl_xor(m, off));
  float sum = 0.f;
  for (int p = p0 + lane; p < p1; p += 16){
    float s = 1.f/(1.f + __expf(-(a_src[csr_src[p]] + ad)));
    float e = __expf(s - m);
    csr_alpha[p] = e;
    sum += e;
  }
  #pragma unroll
  for (int off=8; off>0; off>>=1) sum += __shfl_xor(sum, off);
  float inv = 1.f/(sum + 1e-16f);
  for (int p = p0 + lane; p < p1; p += 16) csr_alpha[p] *= inv;
}

// ---------------- conv1 aggregate (512-wide) ----------------
__global__ __launch_bounds__(256) void agg_kernel(const ushort* __restrict__ X,
    const int* __restrict__ row_ptr, const int* __restrict__ csr_src,
    const float* __restrict__ csr_alpha, ushort* __restrict__ outb){
  __shared__ float red[3][64*8];
  int v = blockIdx.x;
  int lane = threadIdx.x & 63;
  int q = threadIdx.x >> 6;
  int p0 = row_ptr[v], p1 = row_ptr[v+1];
  float acc[8] = {0.f,0.f,0.f,0.f,0.f,0.f,0.f,0.f};
  for (int p = p0 + q; p < p1; p += 4){
    int s = csr_src[p];
    float al = csr_alpha[p];
    bf16x8 xv = *(const bf16x8*)(X + (size_t)s*HIDD + lane*8);
    #pragma unroll
    for (int j=0;j<8;++j) acc[j] += al * bf2f((ushort)xv[j]);
  }
  if (q > 0){
    #pragma unroll
    for (int j=0;j<8;++j) red[q-1][lane*8+j] = acc[j];
  }
  __syncthreads();
  if (q == 0){
    bf16x8 o;
    #pragma unroll
    for (int j=0;j<8;++j){
      float a = acc[j] + red[0][lane*8+j] + red[1][lane*8+j] + red[2][lane*8+j];
      a = a > 0.f ? a : __expf(a)-1.f;
      o[j] = (short)f2bf(a);
    }
    *(bf16x8*)(outb + (size_t)v*HIDD + lane*8) = o;
  }
}

// ---------------- h2 = h1 @ W2 (K=512, N=30) ----------------
__global__ __launch_bounds__(256) void mid_kernel(const ushort* __restrict__ h1,
    const ushort* __restrict__ W2tc, float* __restrict__ h2){
  __shared__ ushort h1s[32*512];
  __shared__ ushort w2s[32*512];
  const int t = threadIdx.x;
  const int row0 = blockIdx.x * 32;
  const ushort* g = h1 + (size_t)row0*HIDD;
  #pragma unroll
  for (int it=0; it<8; ++it){
    int ch = t + it*256;
    *(bf16x8*)&h1s[ch*8] = *(const bf16x8*)&g[ch*8];
    *(bf16x8*)&w2s[ch*8] = *(const bf16x8*)&W2tc[ch*8];
  }
  __syncthreads();
  int c = t & 31, rg = t >> 5;
  if (c < ODIM){
    float acc[4] = {0.f,0.f,0.f,0.f};
    for (int k0=0;k0<64;++k0){
      bf16x8 wv = *(const bf16x8*)&w2s[c*512 + k0*8];
      #pragma unroll
      for (int rr=0; rr<4; ++rr){
        bf16x8 hv = *(const bf16x8*)&h1s[(rg*4+rr)*HIDD + k0*8];
        #pragma unroll
        for (int j=0;j<8;++j) acc[rr] += bf2f((ushort)hv[j]) * bf2f((ushort)wv[j]);
      }
    }
    #pragma unroll
    for (int rr=0;rr<4;++rr) h2[(size_t)(row0 + rg*4 + rr)*ODIM + c] = acc[rr];
  }
}

// ---------------- conv3 aggregate on 30-dim h2 ----------------
__global__ __launch_bounds__(256) void agg30_kernel(const float* __restrict__ h2,
    const int* __restrict__ row_ptr, const int* __restrict__ csr_src,
    const float* __restrict__ csr_alpha, float* __restrict__ g){
  int gid = blockIdx.x*256 + threadIdx.x;
  int v = gid >> 5, lane = gid & 31;
  if (v >= NNODES) return;
  int p0 = row_ptr[v], p1 = row_ptr[v+1];
  float acc = 0.f;
  if (lane < ODIM){
    for (int p = p0; p < p1; ++p){
      acc += csr_alpha[p] * h2[(size_t)csr_src[p]*ODIM + lane];
    }
  }
  g[(size_t)v*32 + lane] = acc;
}

// ---------------- h3 = elu( g @ W2^T ) ----------------
__global__ __launch_bounds__(256) void g2h3_kernel(const float* __restrict__ g,
    const ushort* __restrict__ W2p, ushort* __restrict__ h3){
  int gid = blockIdx.x*256 + threadIdx.x;
  int row = gid >> 6, lane = gid & 63;
  if (row >= NNODES) return;
  float h[ODIM];
  #pragma unroll
  for (int ci=0; ci<ODIM; ++ci) h[ci] = g[(size_t)row*32 + ci];
  #pragma unroll
  for (int it=0; it<8; ++it){
    int n = it*64 + lane;
    const ushort* wr = W2p + n*32;
    bf16x8 wvv[4];
    #pragma unroll
    for (int q=0;q<4;++q) wvv[q] = *(const bf16x8*)(wr + q*8);
    float acc = 0.f;
    #pragma unroll
    for (int ci=0; ci<ODIM; ++ci) acc += h[ci]*bf2f((ushort)wvv[ci>>3][ci&7]);
    acc = acc > 0.f ? acc : __expf(acc)-1.f;
    h3[(size_t)row*HIDD + n] = f2bf(acc);
  }
}

extern "C" void kernel_launch(void* const* d_in, const int* in_sizes, int n_in,
                              void* d_out, int out_size, void* d_ws, size_t ws_size,
                              hipStream_t stream){
  const float* features = (const float*)d_in[0];
  const float* W1 = (const float*)d_in[1];
  const float* W2 = (const float*)d_in[2];
  const float* att_src = (const float*)d_in[3];
  const float* att_dst = (const float*)d_in[4];
  const int* edge = (const int*)d_in[5];
  const int* esrc = edge;
  const int* edst = edge + NEDGES;

  float* h2 = (float*)d_out;                              // [40000][30]
  float* h4 = h2 + (size_t)NNODES*ODIM;                   // [40000][2000]
  char* obase = (char*)h4;                                // scratch until GEMM4
  ushort* featb = (ushort*)obase;                         // [40000][2048] bf16
  ushort* x1b   = (ushort*)(obase + 163840000);           // [40000][512]
  ushort* h1b   = (ushort*)(obase + 204800000);

  char* wbase = (char*)d_ws;
  size_t o = 0;
  auto walloc = [&](size_t bytes)->void*{ void* p = wbase + o; o += (bytes + 255) & ~(size_t)255; return p; };
  ushort* h3b      = (ushort*)walloc((size_t)NNODES*HIDD*2);
  ushort* W1b      = (ushort*)walloc((size_t)INDIM*HIDD*2);
  ushort* W1t      = (ushort*)walloc((size_t)HIDD*KPAD*2);
  ushort* W2p      = (ushort*)walloc(512*32*2);
  ushort* W2tc     = (ushort*)walloc(32*512*2);
  float*  a_src    = (float*)walloc(NNODES*4);
  float*  a_dst    = (float*)walloc(NNODES*4);
  int*    deg      = (int*)walloc(NNODES*4);
  int*    cursor   = (int*)walloc(NNODES*4);
  int*    row_ptr  = (int*)walloc((NNODES+1)*4);
  int*    csr_src  = (int*)walloc(NEDGES*4);
  float*  csr_alpha= (float*)walloc(NEDGES*4);
  float*  gbuf     = (float*)walloc((size_t)NNODES*32*4);

  hipMemsetAsync(deg, 0, NNODES*4, stream);
  hipMemsetAsync(cursor, 0, NNODES*4, stream);
  hipMemsetAsync(W1t, 0, (size_t)HIDD*KPAD*2, stream);

  cast_feat_kernel<<<40000, 256, 0, stream>>>(features, featb);
  cast_w1_kernel<<<(INDIM*HIDD+255)/256, 256, 0, stream>>>(W1, W1b, W1t);
  cast_w2_kernel<<<(HIDD*32+255)/256, 256, 0, stream>>>(W2, W2p, W2tc);
  hist_kernel<<<(NEDGES+255)/256, 256, 0, stream>>>(edst, deg);
  scan_kernel<<<1, 1024, 0, stream>>>(deg, row_ptr);
  place_kernel<<<(NEDGES+255)/256, 256, 0, stream>>>(esrc, edst, row_ptr, cursor, csr_src);

  gemm8_kernel<ushort><<<dim3(2, 157), 512, 0, stream>>>(featb, W1t, x1b, NNODES, HIDD, KPAD, HIDD);
  a_kernel<<<10000, 256, 0, stream>>>(x1b, att_src, att_dst, a_src, a_dst);
  alpha_kernel<<<2500, 256, 0, stream>>>(row_ptr, csr_src, a_src, a_dst, csr_alpha);
  agg_kernel<<<NNODES, 256, 0, stream>>>(x1b, row_ptr, csr_src, csr_alpha, h1b);
  mid_kernel<<<NNODES/32, 256, 0, stream>>>(h1b, W2tc, h2);
  agg30_kernel<<<NNODES*32/256, 256, 0, stream>>>(h2, row_ptr, csr_src, csr_alpha, gbuf);
  g2h3_kernel<<<10000, 256, 0, stream>>>(gbuf, W2p, h3b);
  gemm8_kernel<float><<<dim3(8, 157), 512, 0, stream>>>(h3b, W1b, h4, NNODES, INDIM, HIDD, INDIM);
}